// Round 2
// baseline (93.500 us; speedup 1.0000x reference)
//
#include <hip/hip_runtime.h>

#define A_ 8732
#define B_ 32
#define N_ 100
#define NT 35              // anchor tiles of 256 (ceil(A_/256)); last tile has 28
#define GB 4               // GTs per reduction chunk
#define EPSF 1e-6f

// ws layout (every slot later read is written this launch — poison-proof):
//   pbest [B_*A_]    u64: per-anchor best key (iou<<32)|(99-n), init (0,n=0)
//   wsplit[B_*NT*N_] u64: per-(tile,GT) best key (iou<<32)|(~a); invalid GTs
//                         get (0,~tile_first_anchor) -> global merge = anchor 0
//                         (numpy zero-column argmax), exactly.

// ---------------------------------------------------------------------------
// K1: block (t, b) owns anchors [t*256, min(A_, t*256+256)); thread tid owns
// anchor a = t*256+tid. ONE IoU evaluation per (a, GT) drives BOTH argmax
// directions (bit-identical keys — the invariant the absmax-0 kernel proved;
// recomputing IoU in a second context risks different -ffp-contract fusion
// vs the unfused numpy reference and flips near-tie argmaxes).
//  Phase 0: deterministic compaction of valid GTs (z>x && w>y) into LDS.
//           Inverted GTs have IoU == +0 vs every anchor (rx<=x1<x0<=lx => w=0)
//           and are exactly covered by the init keys.
//  Main loop: chunks of 4 compacted GTs; per thread update per-anchor key
//           ak (iou<<32)|(99-n) and 4 per-GT keys wk[j] (iou<<32)|(~a),
//           per-lane init (0,~a) -> reduces to (0,~a0) for a zero column.
//           6-round shfl_xor per-wave max + 4-entry cross-wave LDS merge
//           -> wsplit[b][t][n]. Equal iou -> smaller n / smaller a
//           (first-occurrence, matches jnp/np argmax).
// ---------------------------------------------------------------------------
__global__ __launch_bounds__(256) void k_scan(
    const float* __restrict__ gt, const float* __restrict__ anchors,
    unsigned long long* __restrict__ pbest,
    unsigned long long* __restrict__ wsplit) {
  int tid = threadIdx.x;
  int lane = tid & 63, wid = tid >> 6;
  int t = blockIdx.x, b = blockIdx.y;
  int a0 = t * 256;
  int a = a0 + tid;

  __shared__ unsigned long long s_bal[2];
  __shared__ float4 s_cgt[N_];   // compacted valid GT boxes (xyxy)
  __shared__ float s_gar[N_];    // compacted GT areas (verbatim expr)
  __shared__ int s_cn[N_];       // compacted -> original n
  __shared__ unsigned long long s_w[4][GB];

  // ---- load GTs, validity ballot ----
  bool v = false;
  float4 myg;
  if (tid < N_) {
    myg = ((const float4*)gt)[b * N_ + tid];
    v = (myg.z > myg.x && myg.w > myg.y);
  }
  unsigned long long bal = __ballot(v);
  if (lane == 0 && wid < 2) s_bal[wid] = bal;

  // ---- own-anchor xyxy (degenerate box for a>=A_: IoU==0 vs everything) ----
  float ax0 = 2.0f, ay0 = 2.0f, ax1 = 2.0f, ay1 = 2.0f, area_a = 0.0f;
  if (a < A_) {
    float4 an = ((const float4*)anchors)[a];
    ax0 = an.x - an.z * 0.5f;
    ay0 = an.y - an.w * 0.5f;
    ax1 = an.x + an.z * 0.5f;
    ay1 = an.y + an.w * 0.5f;
    area_a = (ax1 - ax0) * (ay1 - ay0);
  }
  __syncthreads();

  int c0 = __popcll(s_bal[0]);
  int c = c0 + __popcll(s_bal[1]);  // waves 2,3: tid>=128 -> v=false
  if (tid < N_) {
    if (v) {
      int rank = __popcll(bal & ((1ull << lane) - 1)) + (wid ? c0 : 0);
      s_cgt[rank] = myg;
      s_gar[rank] = (myg.z - myg.x) * (myg.w - myg.y);
      s_cn[rank] = tid;
    } else {
      // invalid GT: tile-local zero-column winner = first anchor of tile
      wsplit[((size_t)b * NT + t) * N_ + tid] =
          (unsigned long long)(0xFFFFFFFFu - (unsigned)a0);
    }
  }
  __syncthreads();

  unsigned long long ak = (unsigned long long)(unsigned)(N_ - 1);  // (0, n=0)
  unsigned kinvA = 0xFFFFFFFFu - (unsigned)a;  // ~own anchor; last-tile lanes
  // with a>=A_ have smaller inv than lane 0's valid ~a0 -> never surface.

  for (int pc = 0; pc < c; pc += GB) {  // c block-uniform -> uniform barriers
    // ---- load this chunk's 4 GTs (dummy inverted box when past c) ----
    float gx0[GB], gy0[GB], gx1[GB], gy1[GB], gar[GB];
#pragma unroll
    for (int j = 0; j < GB; j++) {
      int p = pc + j;
      bool live = p < c;
      float4 gb = live ? s_cgt[p] : make_float4(1.0f, 1.0f, 0.0f, 0.0f);
      gx0[j] = gb.x; gy0[j] = gb.y; gx1[j] = gb.z; gy1[j] = gb.w;
      gar[j] = live ? s_gar[p] : 0.0f;
    }

    unsigned long long wk[GB];
#pragma unroll
    for (int j = 0; j < GB; j++) wk[j] = (unsigned long long)kinvA;

    // ---- single IoU evaluation -> both keys ----
#pragma unroll
    for (int j = 0; j < GB; j++) {
      float lx = fmaxf(ax0, gx0[j]), ly = fmaxf(ay0, gy0[j]);
      float rx = fminf(ax1, gx1[j]), ry = fminf(ay1, gy1[j]);
      float w = fmaxf(rx - lx, 0.0f), h = fmaxf(ry - ly, 0.0f);
      float inter = w * h;
      if (inter > 0.0f) {  // exact skip: zero-iou covered by inits
        float uni = area_a + gar[j] - inter;
        float iou = inter / fmaxf(uni, EPSF);
        unsigned long long hi = ((unsigned long long)__float_as_uint(iou)) << 32;
        int p = pc + j;
        int nj = (p < c) ? s_cn[p] : 0;
        unsigned long long kA =
            hi | (unsigned long long)(unsigned)(N_ - 1 - nj);
        if (kA > ak) ak = kA;
        unsigned long long kB = hi | (unsigned long long)kinvA;
        if (kB > wk[j]) wk[j] = kB;
      }
    }

    // ---- per-GT reduction: in-wave shfl_xor max, then cross-wave merge ----
#pragma unroll
    for (int j = 0; j < GB; j++) {
      unsigned long long k = wk[j];
#pragma unroll
      for (int off = 32; off; off >>= 1) {
        unsigned long long o = __shfl_xor(k, off, 64);
        if (o > k) k = o;
      }
      if (lane == 0) s_w[wid][j] = k;
    }
    __syncthreads();
    if (tid < GB && pc + tid < c) {
      unsigned long long k = s_w[0][tid];
#pragma unroll
      for (int w2 = 1; w2 < 4; w2++)
        if (s_w[w2][tid] > k) k = s_w[w2][tid];
      wsplit[((size_t)b * NT + t) * N_ + s_cn[pc + tid]] = k;
    }
    __syncthreads();  // protect s_w reuse in next chunk
  }

  if (a < A_) pbest[(size_t)b * A_ + a] = ak;
}

// ---------------------------------------------------------------------------
// K2: per (b, 256-anchor tile). Per-n global winner = max over 35 tile keys
// (coalesced: lane n reads consecutive u64 per tile plane). Override via LDS
// atomicMax over n (= last-write-wins index_put; invalid GTs decode to
// anchor 0 through their init keys). Per-anchor result read from pbest.
// Encode expressions verbatim.
// ---------------------------------------------------------------------------
__global__ __launch_bounds__(256) void k_finalize(
    const float* __restrict__ gt, const int* __restrict__ labels,
    const float* __restrict__ anchors, const unsigned char* __restrict__ mask,
    const unsigned long long* __restrict__ pbest,
    const unsigned long long* __restrict__ wsplit, float* __restrict__ out) {
  int b = blockIdx.y;
  int a0 = blockIdx.x * 256;
  int tid = threadIdx.x;
  int a = a0 + tid;

  __shared__ int s_ov[256];
  __shared__ int s_any;

  if (tid == 0) s_any = 0;
  s_ov[tid] = -1;
  __syncthreads();

  if (tid < N_) {
    const unsigned long long* wp = wsplit + (size_t)b * NT * N_ + tid;
    unsigned long long k = wp[0];
#pragma unroll
    for (int t2 = 1; t2 < NT; t2++) {
      unsigned long long tk = wp[(size_t)t2 * N_];
      if (tk > k) k = tk;
    }
    int aw = (int)(0xFFFFFFFFu - (unsigned)(k & 0xFFFFFFFFull));
    if (aw >= a0 && aw < a0 + 256) atomicMax(&s_ov[aw - a0], tid);
  }
  if (tid < 25) {
    unsigned mv = ((const unsigned*)mask)[b * 25 + tid];
    if (mv) atomicOr(&s_any, 1);
  }
  __syncthreads();
  if (a >= A_) return;

  unsigned long long k = pbest[(size_t)b * A_ + a];
  float iou = __uint_as_float((unsigned)(k >> 32));
  int gi = (N_ - 1) - (int)(k & 0xFFFFFFFFull);

  int ov = s_ov[tid];
  bool pos;
  if (ov >= 0) {
    gi = ov;
    pos = true;  // scattered best_gt_iou = 2.0 > 0.5
  } else {
    pos = iou > 0.5f;
  }

  float4 an = ((const float4*)anchors)[a];
  const float* g = gt + (size_t)(b * N_ + gi) * 4;
  float gx = g[0], gy = g[1], gw = g[2], gh = g[3];

  float ex = (gx - an.x) / an.z;
  float ey = (gy - an.y) / an.w;
  float ew = logf((gw + EPSF) / (an.z + EPSF));
  float eh = logf((gh + EPSF) / (an.w + EPSF));
  int lab = pos ? labels[b * N_ + gi] : 0;

  if (!s_any) { ex = 0.0f; ey = 0.0f; ew = 0.0f; eh = 0.0f; lab = 0; }

  const long long BA = (long long)B_ * A_;
  ((float4*)out)[(size_t)b * A_ + a] = make_float4(ex, ey, ew, eh);
  out[4 * BA + (size_t)b * A_ + a] = (float)lab;
  out[5 * BA + (size_t)b * A_ + a] = pos ? 1.0f : 0.0f;
}

extern "C" void kernel_launch(void* const* d_in, const int* in_sizes, int n_in,
                              void* d_out, int out_size, void* d_ws,
                              size_t ws_size, hipStream_t stream) {
  const float* gt = (const float*)d_in[0];
  const int* labels = (const int*)d_in[1];
  const unsigned char* mask = (const unsigned char*)d_in[2];
  const float* anchors = (const float*)d_in[3];
  float* out = (float*)d_out;

  unsigned long long* pbest = (unsigned long long*)d_ws;  // B_*A_
  unsigned long long* wsplit = pbest + (size_t)B_ * A_;   // B_*NT*N_

  k_scan<<<dim3(NT, B_), 256, 0, stream>>>(gt, anchors, pbest, wsplit);
  k_finalize<<<dim3(NT, B_), 256, 0, stream>>>(gt, labels, anchors, mask,
                                               pbest, wsplit, out);
}

// Round 3
// 83.051 us; speedup vs baseline: 1.1258x; 1.1258x over previous
//
#include <hip/hip_runtime.h>

#define A_ 8732
#define B_ 32
#define N_ 100
#define ABLK 35            // ceil(A_/256)
#define GB_G 4             // GTs per scan block
#define GMAX 25            // max groups per batch (N_/GB_G)
#define SPLIT 8            // anchor-axis splits per group
#define SLEN 1092          // ceil(A_/SPLIT); last split = 1088 (>=256)
#define EPSF 1e-6f

// ws layout (every slot later read is written this launch — poison-proof):
//   partial[B_*GMAX*A_] u64 (only planes g<ceil(c/4) written+read)
//   wsplit [B_*SPLIT*N_] u64 (only valid-n slots written+read)
//   cgt[B_*N_] float4, car[B_*N_] f32, cn[B_*N_] i32 (only rank<c slots)
//   cnt[B_] i32, vmask[B_*2] u64 (always written)

// ---------------------------------------------------------------------------
// K0: per-batch deterministic compaction of valid GTs (z>x && w>y), rank =
// ascending original n (ballot prefix) — identical order to the in-block
// compaction of the verified baseline. Inverted GTs have IoU == +0 vs EVERY
// anchor (rx <= x1 < x0 <= lx => w=0) and are handled exactly by the
// zero-key inits downstream. Area expr verbatim; same bits in -> same bits
// stored -> bit-identical keys in K1.
// ---------------------------------------------------------------------------
__global__ __launch_bounds__(128) void k_compact(
    const float* __restrict__ gt, float4* __restrict__ cgt,
    float* __restrict__ car, int* __restrict__ cn, int* __restrict__ cnt,
    unsigned long long* __restrict__ vmask) {
  int b = blockIdx.x;
  int tid = threadIdx.x;
  int lane = tid & 63, wid = tid >> 6;
  __shared__ unsigned long long s_bal[2];

  bool v = false;
  float4 myg;
  if (tid < N_) {
    myg = ((const float4*)gt)[b * N_ + tid];
    v = (myg.z > myg.x && myg.w > myg.y);
  }
  unsigned long long bal = __ballot(v);
  if (lane == 0) {
    s_bal[wid] = bal;
    vmask[b * 2 + wid] = bal;
  }
  __syncthreads();
  int c0 = __popcll(s_bal[0]);
  int c = c0 + __popcll(s_bal[1]);
  if (v) {
    int rank = __popcll(bal & ((1ull << lane) - 1)) + (wid ? c0 : 0);
    cgt[b * N_ + rank] = myg;
    car[b * N_ + rank] = (myg.z - myg.x) * (myg.w - myg.y);
    cn[b * N_ + rank] = tid;
  }
  if (tid == 0) cnt[b] = c;
}

// ---------------------------------------------------------------------------
// K1: block (b, g, s) scans anchors [s*SLEN, min(A_,(s+1)*SLEN)) for the 4
// GTs of compacted group g; BOTH directions in one pass (single IoU eval per
// (a,GT) pair drives both keys — bit-identical, the verified invariant):
//  - per-anchor partial key (iou<<32)|(99-n) -> prow[a] (one writer per a).
//  - per-GT key (iou<<32)|(inv a); per-lane init (0, inv(first lane anchor));
//    in-wave shfl_xor max (6 rounds, no barriers) + 4-entry cross-wave LDS
//    merge -> wsplit[b][s][n]. Cross-split max in finalize keeps global
//    first-occurrence (inv strictly decreasing in a).
// Dead blocks (4*g >= c) exit after ONE broadcast load — no gt loads, no
// ballot, no barriers (c is block-uniform, so barrier use stays uniform).
// ---------------------------------------------------------------------------
__global__ __launch_bounds__(256) void k_scan(
    const float4* __restrict__ cgt, const float* __restrict__ car,
    const int* __restrict__ cn, const int* __restrict__ cnt,
    const float* __restrict__ anchors,
    unsigned long long* __restrict__ partial,
    unsigned long long* __restrict__ wsplit) {
  int tid = threadIdx.x;
  int lane = tid & 63, wid = tid >> 6;
  int bid = blockIdx.x;
  int s = bid % SPLIT;
  int t = bid / SPLIT;
  int g = t % GMAX;
  int b = t / GMAX;

  __shared__ unsigned long long s_w[4][GB_G];

  int c = cnt[b];
  if (GB_G * g >= c) return;

  // ---- load this group's 4 compacted GTs (dummy inverted box past c) ----
  float gx0[GB_G], gy0[GB_G], gx1[GB_G], gy1[GB_G], gar[GB_G];
  int gn[GB_G];
#pragma unroll
  for (int j = 0; j < GB_G; j++) {
    int p = GB_G * g + j;
    bool live = p < c;
    float4 gb = live ? cgt[b * N_ + p] : make_float4(1.0f, 1.0f, 0.0f, 0.0f);
    gx0[j] = gb.x; gy0[j] = gb.y; gx1[j] = gb.z; gy1[j] = gb.w;
    gar[j] = live ? car[b * N_ + p] : 0.0f;
    gn[j] = live ? cn[b * N_ + p] : 0;
  }

  int s0 = s * SLEN;
  int send = (s0 + SLEN < A_) ? (s0 + SLEN) : A_;

  unsigned long long wkey[GB_G];
#pragma unroll
  for (int j = 0; j < GB_G; j++)
    wkey[j] = (unsigned long long)(0xFFFFFFFFu - (unsigned)(s0 + tid));

  unsigned long long* prow = partial + ((size_t)b * GMAX + g) * A_;
  for (int a = s0 + tid; a < send; a += 256) {
    float4 an = ((const float4*)anchors)[a];
    float ax0 = an.x - an.z * 0.5f, ay0 = an.y - an.w * 0.5f;
    float ax1 = an.x + an.z * 0.5f, ay1 = an.y + an.w * 0.5f;
    float area_a = (ax1 - ax0) * (ay1 - ay0);
    unsigned long long pk = 0ull;
#pragma unroll
    for (int j = 0; j < GB_G; j++) {
      float lx = fmaxf(ax0, gx0[j]), ly = fmaxf(ay0, gy0[j]);
      float rx = fminf(ax1, gx1[j]), ry = fminf(ay1, gy1[j]);
      float w = fmaxf(rx - lx, 0.0f), h = fmaxf(ry - ly, 0.0f);
      float inter = w * h;
      if (inter > 0.0f) {  // exact skip: zero-iou covered by inits
        float uni = area_a + gar[j] - inter;
        float iou = inter / fmaxf(uni, EPSF);
        unsigned long long hi = ((unsigned long long)__float_as_uint(iou)) << 32;
        unsigned long long kA = hi | (unsigned long long)(unsigned)(N_ - 1 - gn[j]);
        if (kA > pk) pk = kA;
        unsigned long long kB = hi | (unsigned long long)(0xFFFFFFFFu - (unsigned)a);
        if (kB > wkey[j]) wkey[j] = kB;
      }
    }
    prow[a] = pk;
  }

  // ---- per-GT reduction: in-wave shfl_xor max, then cross-wave merge ----
#pragma unroll
  for (int j = 0; j < GB_G; j++) {
    unsigned long long k = wkey[j];
#pragma unroll
    for (int off = 32; off; off >>= 1) {
      unsigned long long o = __shfl_xor(k, off, 64);
      if (o > k) k = o;
    }
    if (lane == 0) s_w[wid][j] = k;
  }
  __syncthreads();
  if (tid < GB_G) {
    int j = tid;
    int p = GB_G * g + j;
    if (p < c) {
      unsigned long long k = s_w[0][j];
#pragma unroll
      for (int w2 = 1; w2 < 4; w2++)
        if (s_w[w2][j] > k) k = s_w[w2][j];
      wsplit[((size_t)b * SPLIT + s) * N_ + cn[b * N_ + p]] = k;
    }
  }
}

// ---------------------------------------------------------------------------
// K2: per (b, 256-anchor tile) — c and validity read from K0's outputs (no
// per-block re-ballot). Per-n winner: inverted GT -> aw=0 (numpy zero-column
// argmax); valid -> max over 8 split keys. Override via LDS atomicMax over n
// (= last-write-wins index_put). Per-anchor merge from init (0,99) (decodes
// gi=0; dominates all zero-iou candidates and 0ull partials). Encode
// expressions verbatim.
// ---------------------------------------------------------------------------
__global__ __launch_bounds__(256) void k_finalize(
    const float* __restrict__ gt, const int* __restrict__ labels,
    const float* __restrict__ anchors, const unsigned char* __restrict__ mask,
    const int* __restrict__ cnt, const unsigned long long* __restrict__ vmask,
    const unsigned long long* __restrict__ partial,
    const unsigned long long* __restrict__ wsplit, float* __restrict__ out) {
  int b = blockIdx.y;
  int a0 = blockIdx.x * 256;
  int tid = threadIdx.x;
  int a = a0 + tid;

  __shared__ int s_ov[256];
  __shared__ int s_any;
  __shared__ unsigned long long s_vm[2];

  if (tid == 0) s_any = 0;
  if (tid < 2) s_vm[tid] = vmask[b * 2 + tid];
  s_ov[tid] = -1;
  __syncthreads();

  int c = cnt[b];
  if (tid < N_) {
    bool v = (s_vm[tid >> 6] >> (tid & 63)) & 1;
    int aw = 0;  // inverted GT: all-zero column -> argmax anchor 0
    if (v) {
      const unsigned long long* wp = wsplit + (size_t)b * SPLIT * N_ + tid;
      unsigned long long k = wp[0];
#pragma unroll
      for (int s2 = 1; s2 < SPLIT; s2++) {
        unsigned long long tk = wp[(size_t)s2 * N_];
        if (tk > k) k = tk;
      }
      aw = (int)(0xFFFFFFFFu - (unsigned)(k & 0xFFFFFFFFull));
    }
    if (aw >= a0 && aw < a0 + 256) atomicMax(&s_ov[aw - a0], tid);
  }
  if (tid < 25) {
    unsigned mv = ((const unsigned*)mask)[b * 25 + tid];
    if (mv) atomicOr(&s_any, 1);
  }
  __syncthreads();
  if (a >= A_) return;

  int G = (c + GB_G - 1) / GB_G;  // block-uniform
  unsigned long long k = (unsigned long long)(unsigned)(N_ - 1);  // (0, n=0)
  const unsigned long long* prow = partial + (size_t)b * GMAX * A_ + a;
  for (int g2 = 0; g2 < G; g2++) {
    unsigned long long t2 = prow[(size_t)g2 * A_];
    if (t2 > k) k = t2;
  }
  float iou = __uint_as_float((unsigned)(k >> 32));
  int gi = (N_ - 1) - (int)(k & 0xFFFFFFFFull);

  int ov = s_ov[tid];
  bool pos;
  if (ov >= 0) {
    gi = ov;
    pos = true;  // scattered best_gt_iou = 2.0 > 0.5
  } else {
    pos = iou > 0.5f;
  }

  float4 an = ((const float4*)anchors)[a];
  const float* g = gt + (size_t)(b * N_ + gi) * 4;
  float gx = g[0], gy = g[1], gw = g[2], gh = g[3];

  float ex = (gx - an.x) / an.z;
  float ey = (gy - an.y) / an.w;
  float ew = logf((gw + EPSF) / (an.z + EPSF));
  float eh = logf((gh + EPSF) / (an.w + EPSF));
  int lab = pos ? labels[b * N_ + gi] : 0;

  if (!s_any) { ex = 0.0f; ey = 0.0f; ew = 0.0f; eh = 0.0f; lab = 0; }

  const long long BA = (long long)B_ * A_;
  ((float4*)out)[(size_t)b * A_ + a] = make_float4(ex, ey, ew, eh);
  out[4 * BA + (size_t)b * A_ + a] = (float)lab;
  out[5 * BA + (size_t)b * A_ + a] = pos ? 1.0f : 0.0f;
}

extern "C" void kernel_launch(void* const* d_in, const int* in_sizes, int n_in,
                              void* d_out, int out_size, void* d_ws,
                              size_t ws_size, hipStream_t stream) {
  const float* gt = (const float*)d_in[0];
  const int* labels = (const int*)d_in[1];
  const unsigned char* mask = (const unsigned char*)d_in[2];
  const float* anchors = (const float*)d_in[3];
  float* out = (float*)d_out;

  char* w = (char*)d_ws;
  unsigned long long* partial = (unsigned long long*)w;  // B*GMAX*A
  w += (size_t)B_ * GMAX * A_ * 8;
  unsigned long long* wsplit = (unsigned long long*)w;   // B*SPLIT*N
  w += (size_t)B_ * SPLIT * N_ * 8;
  float4* cgt = (float4*)w;                              // B*N
  w += (size_t)B_ * N_ * 16;
  float* car = (float*)w;                                // B*N
  w += (size_t)B_ * N_ * 4;
  int* cn = (int*)w;                                     // B*N
  w += (size_t)B_ * N_ * 4;
  int* cnt = (int*)w;                                    // B
  w += (size_t)B_ * 4 + 4;  // pad to 8B
  unsigned long long* vmask = (unsigned long long*)w;    // B*2

  k_compact<<<B_, 128, 0, stream>>>(gt, cgt, car, cn, cnt, vmask);
  k_scan<<<B_ * GMAX * SPLIT, 256, 0, stream>>>(cgt, car, cn, cnt, anchors,
                                                partial, wsplit);
  k_finalize<<<dim3(ABLK, B_), 256, 0, stream>>>(gt, labels, anchors, mask,
                                                 cnt, vmask, partial, wsplit,
                                                 out);
}